// Round 14
// baseline (152.201 us; speedup 1.0000x reference)
//
#include <hip/hip_runtime.h>

typedef unsigned short u16;
typedef __attribute__((ext_vector_type(4))) float f32x4;
typedef __attribute__((ext_vector_type(16))) float f32x16;
typedef __attribute__((ext_vector_type(8))) __bf16 bf16x8;
typedef __attribute__((ext_vector_type(8))) u16 u16x8;
typedef __attribute__((ext_vector_type(4))) u16 u16x4;
typedef __attribute__((ext_vector_type(4))) unsigned int u32x4;

#define S_LEN 2048
#define NH 16
#define NKV 8
// sqrt(128) * log2(e) folded into Q; softmax runs in exp2 space
#define QSCALE_LOG2E 16.322118857f
#define M2INIT 16.6f   /* fixed max: |s2| <= 16.33*(1+eps) -> shift-exact */
#define EXP2(x) __builtin_amdgcn_exp2f(x)

// attn swizzles (round-9/10, verified)
#define SWZK(r) (((((r) & 7) << 4)) ^ (((((r) >> 3) & 1)) << 7))   /* 256B rows */
#define SWZV(r) (((((r) & 7) << 4)) ^ (((((r) >> 3) & 1)) << 6))   /* 128B rows */

#define AS1(p) ((const __attribute__((address_space(1))) void*)(p))
#define AS3(p) ((__attribute__((address_space(3))) void*)(p))

// counted-vmcnt + raw barrier, one asm block so nothing interleaves.
#define PIPE_WAIT6() asm volatile("s_waitcnt vmcnt(6)\ns_barrier" ::: "memory")
#define PIPE_WAIT0() asm volatile("s_waitcnt vmcnt(0)\ns_barrier" ::: "memory")

__device__ __forceinline__ float b2f(u16 u) {
    return __uint_as_float(((unsigned int)u) << 16);
}
__device__ __forceinline__ u16 f2b(float f) {
    unsigned int x = __float_as_uint(f);
    unsigned int r = (x + 0x7FFFu + ((x >> 16) & 1u)) >> 16;
    return (u16)r;
}

// ---------------------------------------------------------------- fused casts
__global__ __launch_bounds__(256) void cast_all(const float* __restrict__ hs,
                                                const float* __restrict__ Wq,
                                                const float* __restrict__ Wk,
                                                const float* __restrict__ Wv,
                                                const float* __restrict__ Wo,
                                                u16* __restrict__ hsb,
                                                u16* __restrict__ wcat,
                                                u16* __restrict__ wob) {
    int i = blockIdx.x * 256 + threadIdx.x;   // 0 .. 4194303 quads
    const float* src; u16* dst; int off;
    if (i < 1048576)      { src = hs; dst = hsb;            off = i; }
    else if (i < 2097152) { src = Wq; dst = wcat;           off = i - 1048576; }
    else if (i < 2621440) { src = Wk; dst = wcat + 4194304; off = i - 2097152; }
    else if (i < 3145728) { src = Wv; dst = wcat + 6291456; off = i - 2621440; }
    else                  { src = Wo; dst = wob;            off = i - 3145728; }
    f32x4 v = reinterpret_cast<const f32x4*>(src)[off];
    u16x4 o;
    o[0] = f2b(v[0]); o[1] = f2b(v[1]); o[2] = f2b(v[2]); o[3] = f2b(v[3]);
    reinterpret_cast<u16x4*>(dst)[off] = o;
}

// ---------------------------------------------------------------- fused QKV GEMM
// 3-buf counted-vmcnt pipeline (r10) with 32x32x16 MFMA: 2x FLOP per
// instruction and per fragment pair -> halves the per-tile MFMA issue count.
// Wave tile 32 rows x 128 cols (one head): acc[4] f32x16 (n-tiles of 32 cols).
// Layouts (attn-verified): A row=l31 k=hi*8+j; B col=l31; C/D col=l31,
// row=(reg&3)+8(reg>>2)+4hi. Rope pair (d,d+64) = (acc[n],acc[n+2]) lane-local.
__global__ __launch_bounds__(512) void gemm_qkv(const u16* __restrict__ A,     // hsb
                                                const u16* __restrict__ B,     // wcat
                                                const float* __restrict__ cosb,
                                                const float* __restrict__ sinb,
                                                const float* __restrict__ sqkw,
                                                u16* __restrict__ qb,          // [16][S][128]
                                                u16* __restrict__ kb,          // [8][S][128]
                                                u16* __restrict__ vt) {        // [1024][S]
    const int K = 2048;
    __shared__ alignas(16) u16 As[3][128 * 64];   //  48 KB
    __shared__ alignas(16) u16 Bs[3][256 * 64];   //  96 KB
    int tid = threadIdx.x, lane = tid & 63, wave = tid >> 6;   // 8 waves
    int row0 = blockIdx.y * 128, col0 = blockIdx.x * 256;
    int wr = (wave >> 1) * 32;        // 4 M row-groups
    int wc = (wave & 1) * 128;        // 2 N head-columns
    int l31 = lane & 31, hi = lane >> 5;
    int sw = l31 & 7;                 // row&7 for all frag rows (rows = X + l31, X%32==0)

    f32x16 acc[4] = {};

    auto stage = [&](int bf, int k0) {
#pragma unroll
        for (int i = 0; i < 2; i++) {
            int slot = i * 8 + wave;                 // 0..15 (wave-uniform)
            int r = slot * 8 + (lane >> 3);          // A row 0..127
            int c = (lane & 7) ^ (r & 7);            // inverse-swizzled source chunk
            __builtin_amdgcn_global_load_lds(AS1(A + (size_t)(row0 + r) * K + k0 + c * 8),
                                             AS3(&As[bf][slot * 512]), 16, 0, 0);
        }
#pragma unroll
        for (int i = 0; i < 4; i++) {
            int slot = i * 8 + wave;                 // 0..31
            int r = slot * 8 + (lane >> 3);          // B row 0..255
            int c = (lane & 7) ^ (r & 7);
            __builtin_amdgcn_global_load_lds(AS1(B + (size_t)(col0 + r) * K + k0 + c * 8),
                                             AS3(&Bs[bf][slot * 512]), 16, 0, 0);
        }
    };

    const int nk = K >> 6;            // 32
    stage(0, 0);
    stage(1, 64);

    int rA = wr + l31;
    for (int t = 0; t < nk; ++t) {
        int buf = t % 3;
        __builtin_amdgcn_sched_barrier(0);
        if (t + 1 < nk) PIPE_WAIT6(); else PIPE_WAIT0();
        if (t + 2 < nk) stage((t + 2) % 3, (t + 2) * 64);

        __builtin_amdgcn_s_setprio(1);
#pragma unroll
        for (int ks = 0; ks < 4; ks++) {
            int ch = (ks * 2 + hi) ^ sw;             // LDS 16B-slot (swizzled)
            bf16x8 af = *reinterpret_cast<const bf16x8*>(&As[buf][rA * 64 + ch * 8]);
#pragma unroll
            for (int n = 0; n < 4; n++) {
                int rB = wc + n * 32 + l31;
                bf16x8 bf = *reinterpret_cast<const bf16x8*>(&Bs[buf][rB * 64 + ch * 8]);
                acc[n] = __builtin_amdgcn_mfma_f32_32x32x16_bf16(af, bf, acc[n], 0, 0, 0);
            }
        }
        __builtin_amdgcn_s_setprio(0);
    }

    // epilogue: rope + L2 norm (+ sqk for Q), or V transpose. 32x32 C layout.
    int c32 = blockIdx.x * 2 + (wave & 1);   // 0..15 Q, 16..23 K, 24..31 V
    if (c32 < 24) {
        bool isQ = c32 < 16;
        float w2[4];
        if (isQ) {
#pragma unroll
            for (int n = 0; n < 4; n++) {
                float w = sqkw[c32 * 128 + n * 32 + l31] * 50.f;
                w2[n] = w * w * QSCALE_LOG2E;
            }
        }
        u16* outb = isQ ? (qb + (size_t)c32 * S_LEN * 128)
                        : (kb + (size_t)(c32 - 16) * S_LEN * 128);
#pragma unroll
        for (int q4 = 0; q4 < 4; q4++)
#pragma unroll
            for (int j = 0; j < 4; j++) {
                int reg = q4 * 4 + j;
                int s = row0 + wr + j + 8 * q4 + 4 * hi;
                const float* crow = cosb + (size_t)s * 128;
                const float* srow = sinb + (size_t)s * 128;
                float y[4];
                float ss = 0.f;
#pragma unroll
                for (int n0 = 0; n0 < 2; n0++) {
                    int d0 = n0 * 32 + l31;          // < 64
                    float c0 = crow[d0],      c1 = crow[64 + d0];
                    float s0 = srow[d0],      s1 = srow[64 + d0];
                    float x0 = acc[n0][reg], x1 = acc[n0 + 2][reg];
                    float a = x0 * c0 - x1 * s0;
                    float b = x1 * c1 + x0 * s1;
                    y[n0] = a; y[n0 + 2] = b;
                    ss += a * a + b * b;
                }
                ss += __shfl_xor(ss, 1);
                ss += __shfl_xor(ss, 2);
                ss += __shfl_xor(ss, 4);
                ss += __shfl_xor(ss, 8);
                ss += __shfl_xor(ss, 16);
                float inv = 1.f / (sqrtf(ss) + 1e-8f);
                u16* orow = outb + (size_t)s * 128;
                if (isQ) {
#pragma unroll
                    for (int n = 0; n < 4; n++)
                        orow[n * 32 + l31] = f2b(y[n] * inv * w2[n]);
                } else {
#pragma unroll
                    for (int n = 0; n < 4; n++)
                        orow[n * 32 + l31] = f2b(y[n] * inv);
                }
            }
    } else {
        int g = c32 - 24;
#pragma unroll
        for (int n = 0; n < 4; n++) {
            int d = n * 32 + l31;
            u16* vrow = vt + (size_t)(g * 128 + d) * S_LEN;
#pragma unroll
            for (int q4 = 0; q4 < 4; q4++) {
                u16x4 pk;
#pragma unroll
                for (int j = 0; j < 4; j++) pk[j] = f2b(acc[n][q4 * 4 + j]);
                *reinterpret_cast<u16x4*>(&vrow[row0 + wr + 8 * q4 + 4 * hi]) = pk;
            }
        }
    }
}

// ---------------------------------------------------------------- O-proj GEMM (3-buf counted pipeline, 128x64, 4 waves, 32x32 MFMA)
__global__ __launch_bounds__(256) void gemm_o(const u16* __restrict__ A,
                                              const u16* __restrict__ B,
                                              float* __restrict__ C,
                                              int M, int N, int K) {
    __shared__ alignas(16) u16 As[3][128 * 64];   // 48 KB
    __shared__ alignas(16) u16 Bs[3][64 * 64];    // 24 KB
    int tid = threadIdx.x, lane = tid & 63, wave = tid >> 6;   // 4 waves
    int row0 = blockIdx.y * 128, col0 = blockIdx.x * 64;
    int wr = wave * 32;               // 4M x 1N wave grid
    int l31 = lane & 31, hi = lane >> 5;
    int sw = l31 & 7;

    f32x16 acc[2] = {};

    auto stage = [&](int bf, int k0) {
#pragma unroll
        for (int i = 0; i < 4; i++) {
            int slot = i * 4 + wave;                 // 0..15
            int r = slot * 8 + (lane >> 3);          // A row 0..127
            int c = (lane & 7) ^ (r & 7);
            __builtin_amdgcn_global_load_lds(AS1(A + (size_t)(row0 + r) * K + k0 + c * 8),
                                             AS3(&As[bf][slot * 512]), 16, 0, 0);
        }
#pragma unroll
        for (int i = 0; i < 2; i++) {
            int slot = i * 4 + wave;                 // 0..7
            int r = slot * 8 + (lane >> 3);          // B row 0..63
            int c = (lane & 7) ^ (r & 7);
            __builtin_amdgcn_global_load_lds(AS1(B + (size_t)(col0 + r) * K + k0 + c * 8),
                                             AS3(&Bs[bf][slot * 512]), 16, 0, 0);
        }
    };

    const int nk = K >> 6;
    stage(0, 0);
    stage(1, 64);

    int rA = wr + l31;
    for (int t = 0; t < nk; ++t) {
        int buf = t % 3;
        __builtin_amdgcn_sched_barrier(0);
        if (t + 1 < nk) PIPE_WAIT6(); else PIPE_WAIT0();
        if (t + 2 < nk) stage((t + 2) % 3, (t + 2) * 64);

        __builtin_amdgcn_s_setprio(1);
#pragma unroll
        for (int ks = 0; ks < 4; ks++) {
            int ch = (ks * 2 + hi) ^ sw;
            bf16x8 af = *reinterpret_cast<const bf16x8*>(&As[buf][rA * 64 + ch * 8]);
#pragma unroll
            for (int n = 0; n < 2; n++) {
                int rB = n * 32 + l31;
                bf16x8 bf = *reinterpret_cast<const bf16x8*>(&Bs[buf][rB * 64 + ch * 8]);
                acc[n] = __builtin_amdgcn_mfma_f32_32x32x16_bf16(af, bf, acc[n], 0, 0, 0);
            }
        }
        __builtin_amdgcn_s_setprio(0);
    }

#pragma unroll
    for (int n = 0; n < 2; n++)
#pragma unroll
        for (int reg = 0; reg < 16; reg++) {
            int row = row0 + wr + (reg & 3) + 8 * (reg >> 2) + 4 * hi;
            int col = col0 + n * 32 + l31;
            C[(size_t)row * N + col] = acc[n][reg];
        }
}

// ---------------------------------------------------------------- MFMA flash attention (r12: LDS-staged + XCD remap, unchanged)
__global__ __launch_bounds__(256) void attn_mfma(const u16* __restrict__ Qb,  // [16][S][128]
                                                 const u16* __restrict__ Kb,  // [8][S][128]
                                                 const u16* __restrict__ Vt,  // [1024][S]
                                                 u16* __restrict__ Ao) {      // [S][2048]
    __shared__ alignas(16) char smem[50432];
    u16* Ks = (u16*)smem;                      // [64][256B] 16KB (loop)
    u16* Vs = (u16*)(smem + 16384);            // [128][128B] 16KB (loop)
    float* scrO = (float*)smem;                // [2][128][32] f32 32KB (epilogue)
    float* scrL = (float*)(smem + 32768);      // [2][32] f32 (epilogue)
    u16*   scrT = (u16*)(smem + 33024);        // [64][136] u16 (epilogue)

    int tid = threadIdx.x, lane = tid & 63, wv = tid >> 6;
    int b = blockIdx.x;
    int xcd = b & 7, j = b >> 3;
    int g = xcd;
    int h = xcd * 2 + (j & 1);
    int z = j >> 1;                            // 0..31
    int qi = (z < 16) ? (31 - z) : (z - 16);   // pair big+small per CU
    int qb0 = qi * 64;
    int l31 = lane & 31, hi = lane >> 5;
    int qoff = (wv >> 1) * 32, koff = (wv & 1) * 32;
    int qabs = qb0 + qoff + l31;

    bf16x8 qf[8];
    {
        const u16* qrow = Qb + ((size_t)h * S_LEN + qabs) * 128;
#pragma unroll
        for (int kd = 0; kd < 8; kd++)
            qf[kd] = *reinterpret_cast<const bf16x8*>(qrow + kd * 16 + hi * 8);
    }

    const u16* kbase = Kb + (size_t)g * S_LEN * 128;
    const u16* vbase = Vt + (size_t)g * 128 * S_LEN;

    int rk = wv * 16 + (lane >> 4);
    int ck = lane & 15;
    int rv = wv * 32 + (lane >> 3);
    int cv = lane & 7;

    u16x8 kreg[4], vreg[4];
    f32x16 oacc[4] = {};
    float lpart = 0.f;

    int nt = qi + 1;

#pragma unroll
    for (int i = 0; i < 4; i++) {
        kreg[i] = *reinterpret_cast<const u16x8*>(kbase + (size_t)(rk + 4 * i) * 128 + ck * 8);
        vreg[i] = *reinterpret_cast<const u16x8*>(vbase + (size_t)(rv + 8 * i) * S_LEN + cv * 8);
    }

    for (int t = 0; t < nt; ++t) {
        int k0 = t * 64;
        __syncthreads();
#pragma unroll
        for (int i = 0; i < 4; i++) {
            int r = rk + 4 * i;
            *reinterpret_cast<u16x8*>((char*)Ks + r * 256 + ((ck * 16) ^ SWZK(r))) = kreg[i];
            int r2 = rv + 8 * i;
            *reinterpret_cast<u16x8*>((char*)Vs + r2 * 128 + ((cv * 16) ^ SWZV(r2))) = vreg[i];
        }
        __syncthreads();

        if (t + 1 < nt) {
            int kn = k0 + 64;
#pragma unroll
            for (int i = 0; i < 4; i++) {
                kreg[i] = *reinterpret_cast<const u16x8*>(kbase + (size_t)(kn + rk + 4 * i) * 128 + ck * 8);
                vreg[i] = *reinterpret_cast<const u16x8*>(vbase + (size_t)(rv + 8 * i) * S_LEN + kn + cv * 8);
            }
        }

        f32x16 s0 = {}, s1 = {};
        int krow = koff + l31;
        char* krp = (char*)Ks + krow * 256;
        int ksw = SWZK(krow);
        __builtin_amdgcn_s_setprio(1);
#pragma unroll
        for (int kd = 0; kd < 8; kd += 2) {
            bf16x8 kf0 = *reinterpret_cast<const bf16x8*>(krp + ((kd * 32 + hi * 16) ^ ksw));
            bf16x8 kf1 = *reinterpret_cast<const bf16x8*>(krp + (((kd + 1) * 32 + hi * 16) ^ ksw));
            s0 = __builtin_amdgcn_mfma_f32_32x32x16_bf16(kf0, qf[kd], s0, 0, 0, 0);
            s1 = __builtin_amdgcn_mfma_f32_32x32x16_bf16(kf1, qf[kd + 1], s1, 0, 0, 0);
        }
        __builtin_amdgcn_s_setprio(0);

        float p[16];
        bool maskt = (t == nt - 1);
#pragma unroll
        for (int r = 0; r < 16; r++) {
            float s = s0[r] + s1[r];
            if (maskt) {
                int key = k0 + koff + (r & 3) + 8 * (r >> 2) + 4 * hi;
                if (key > qabs) s = -1e30f;
            }
            float pv = EXP2(s - M2INIT);
            p[r] = pv;
            lpart += pv;
        }

        bf16x8 pf[2];
#pragma unroll
        for (int ks = 0; ks < 2; ks++) {
            int bb = ks * 8;
            unsigned int A0 = (unsigned int)f2b(p[bb + 0]) | ((unsigned int)f2b(p[bb + 1]) << 16);
            unsigned int A1 = (unsigned int)f2b(p[bb + 2]) | ((unsigned int)f2b(p[bb + 3]) << 16);
            unsigned int A2 = (unsigned int)f2b(p[bb + 4]) | ((unsigned int)f2b(p[bb + 5]) << 16);
            unsigned int A3 = (unsigned int)f2b(p[bb + 6]) | ((unsigned int)f2b(p[bb + 7]) << 16);
            unsigned int S0 = __shfl_xor(A0, 32);
            unsigned int S1 = __shfl_xor(A1, 32);
            unsigned int S2 = __shfl_xor(A2, 32);
            unsigned int S3 = __shfl_xor(A3, 32);
            u32x4 w;
            w[0] = hi ? S2 : A0;
            w[1] = hi ? S3 : A1;
            w[2] = hi ? A2 : S0;
            w[3] = hi ? A3 : S1;
            pf[ks] = *reinterpret_cast<bf16x8*>(&w);
        }

        __builtin_amdgcn_s_setprio(1);
#pragma unroll
        for (int db = 0; db < 4; db++) {
            int vr = db * 32 + l31;
            char* vrp = (char*)Vs + vr * 128;
            int vsw = SWZV(vr);
#pragma unroll
            for (int ks = 0; ks < 2; ks++) {
                bf16x8 vf = *reinterpret_cast<const bf16x8*>(vrp + ((koff * 2 + ks * 32 + hi * 16) ^ vsw));
                oacc[db] = __builtin_amdgcn_mfma_f32_32x32x16_bf16(vf, pf[ks], oacc[db], 0, 0, 0);
            }
        }
        __builtin_amdgcn_s_setprio(0);
    }

    float lw = lpart + __shfl_xor(lpart, 32);
    int rg = wv >> 1;
    __syncthreads();
    if (wv & 1) {
#pragma unroll
        for (int db = 0; db < 4; db++)
#pragma unroll
            for (int r = 0; r < 16; r++) {
                int d = db * 32 + (r & 3) + 8 * (r >> 2) + 4 * hi;
                scrO[(rg * 128 + d) * 32 + l31] = oacc[db][r];
            }
        if (lane < 32) scrL[rg * 32 + l31] = lw;
    }
    __syncthreads();
    if (!(wv & 1)) {
        float inv = 1.f / (lw + scrL[rg * 32 + l31]);
#pragma unroll
        for (int db = 0; db < 4; db++)
#pragma unroll
            for (int r = 0; r < 16; r++) {
                int d = db * 32 + (r & 3) + 8 * (r >> 2) + 4 * hi;
                float o = (oacc[db][r] + scrO[(rg * 128 + d) * 32 + l31]) * inv;
                scrT[(rg * 32 + l31) * 136 + d] = f2b(o);
            }
    }
    __syncthreads();
    for (int i = tid; i < 64 * 16; i += 256) {
        int q = i >> 4, c = i & 15;
        u16x8 v = *reinterpret_cast<const u16x8*>(&scrT[q * 136 + c * 8]);
        *reinterpret_cast<u16x8*>(&Ao[(size_t)(qb0 + q) * 2048 + h * 128 + c * 8]) = v;
    }
}

// ---------------------------------------------------------------- launch
extern "C" void kernel_launch(void* const* d_in, const int* in_sizes, int n_in,
                              void* d_out, int out_size, void* d_ws, size_t ws_size,
                              hipStream_t stream) {
    const float* hs   = (const float*)d_in[0];
    const float* cosb = (const float*)d_in[1];
    const float* sinb = (const float*)d_in[2];
    // d_in[3] attention_mask: pure causal, implemented analytically
    const float* Wq   = (const float*)d_in[4];
    const float* Wk   = (const float*)d_in[5];
    const float* Wv   = (const float*)d_in[6];
    const float* Wo   = (const float*)d_in[7];
    const float* sqkw = (const float*)d_in[8];

    char* ws = (char*)d_ws;
    u16*   hsb  = (u16*)(ws);                       //  8.4 MB
    u16*   wcat = (u16*)(ws + 8388608);             // 16.8 MB (Wq;Wk;Wv)
    u16*   wob  = (u16*)(ws + 25165824);            //  8.4 MB
    u16*   qb   = (u16*)(ws + 33554432);            //  8.4 MB  [16][S][128]
    u16*   kb   = (u16*)(ws + 41943040);            //  4.2 MB  [8][S][128]
    u16*   vt   = (u16*)(ws + 46137344);            //  4.2 MB  [1024][S] (V^T)
    u16*   ao   = (u16*)(ws + 50331648);            //  8.4 MB  [S][2048]

    cast_all<<<16384, 256, 0, stream>>>(hs, Wq, Wk, Wv, Wo, hsb, wcat, wob);

    // fused QKV projection + RoPE + L2 norm + sqk scale + V transpose
    gemm_qkv<<<dim3(16, 16), 512, 0, stream>>>(hsb, wcat, cosb, sinb, sqkw, qb, kb, vt);

    attn_mfma<<<512, 256, 0, stream>>>(qb, kb, vt, ao);

    // output projection -> f32 d_out (128x64 tiles, 4 waves, 512 blocks = 2/CU)
    gemm_o<<<dim3(32, 16), 256, 0, stream>>>(ao, wob, (float*)d_out, 2048, 2048, 2048);
}

// Round 15
// 143.509 us; speedup vs baseline: 1.0606x; 1.0606x over previous
//
#include <hip/hip_runtime.h>

typedef unsigned short u16;
typedef __attribute__((ext_vector_type(4))) float f32x4;
typedef __attribute__((ext_vector_type(16))) float f32x16;
typedef __attribute__((ext_vector_type(8))) __bf16 bf16x8;
typedef __attribute__((ext_vector_type(8))) u16 u16x8;
typedef __attribute__((ext_vector_type(4))) u16 u16x4;
typedef __attribute__((ext_vector_type(4))) unsigned int u32x4;

#define S_LEN 2048
#define NH 16
#define NKV 8
// sqrt(128) * log2(e) folded into Q; softmax runs in exp2 space
#define QSCALE_LOG2E 16.322118857f
#define M2INIT 16.6f   /* fixed max: |s2| <= 16.33*(1+eps) -> shift-exact */
#define EXP2(x) __builtin_amdgcn_exp2f(x)

// attn swizzles (round-9/10, verified)
#define SWZK(r) (((((r) & 7) << 4)) ^ (((((r) >> 3) & 1)) << 7))   /* 256B rows */
#define SWZV(r) (((((r) & 7) << 4)) ^ (((((r) >> 3) & 1)) << 6))   /* 128B rows */

#define AS1(p) ((const __attribute__((address_space(1))) void*)(p))
#define AS3(p) ((__attribute__((address_space(3))) void*)(p))

// counted-vmcnt + raw barrier, one asm block so nothing interleaves.
#define PIPE_WAIT6() asm volatile("s_waitcnt vmcnt(6)\ns_barrier" ::: "memory")
#define PIPE_WAIT0() asm volatile("s_waitcnt vmcnt(0)\ns_barrier" ::: "memory")

__device__ __forceinline__ float b2f(u16 u) {
    return __uint_as_float(((unsigned int)u) << 16);
}
__device__ __forceinline__ u16 f2b(float f) {
    unsigned int x = __float_as_uint(f);
    unsigned int r = (x + 0x7FFFu + ((x >> 16) & 1u)) >> 16;
    return (u16)r;
}

// ---------------------------------------------------------------- fused casts
__global__ __launch_bounds__(256) void cast_all(const float* __restrict__ hs,
                                                const float* __restrict__ Wq,
                                                const float* __restrict__ Wk,
                                                const float* __restrict__ Wv,
                                                const float* __restrict__ Wo,
                                                u16* __restrict__ hsb,
                                                u16* __restrict__ wcat,
                                                u16* __restrict__ wob) {
    int i = blockIdx.x * 256 + threadIdx.x;   // 0 .. 4194303 quads
    const float* src; u16* dst; int off;
    if (i < 1048576)      { src = hs; dst = hsb;            off = i; }
    else if (i < 2097152) { src = Wq; dst = wcat;           off = i - 1048576; }
    else if (i < 2621440) { src = Wk; dst = wcat + 4194304; off = i - 2097152; }
    else if (i < 3145728) { src = Wv; dst = wcat + 6291456; off = i - 2621440; }
    else                  { src = Wo; dst = wob;            off = i - 3145728; }
    f32x4 v = reinterpret_cast<const f32x4*>(src)[off];
    u16x4 o;
    o[0] = f2b(v[0]); o[1] = f2b(v[1]); o[2] = f2b(v[2]); o[3] = f2b(v[3]);
    reinterpret_cast<u16x4*>(dst)[off] = o;
}

// ---------------------------------------------------------------- fused QKV GEMM (r10/r12 3-buf counted-vmcnt + T1 XCD remap)
// flat f -> xcd=f&7, i=f>>3; by=2*xcd+(i&1), bx=i>>1: each XCD owns 2 A-panels
// (1MB, L2-resident); B cols swept in lockstep across XCDs (L3 broadcast).
__global__ __launch_bounds__(512) void gemm_qkv(const u16* __restrict__ A,     // hsb
                                                const u16* __restrict__ B,     // wcat
                                                const float* __restrict__ cosb,
                                                const float* __restrict__ sinb,
                                                const float* __restrict__ sqkw,
                                                u16* __restrict__ qb,          // [16][S][128]
                                                u16* __restrict__ kb,          // [8][S][128]
                                                u16* __restrict__ vt) {        // [1024][S]
    const int K = 2048;
    __shared__ alignas(16) u16 As[3][128 * 64];   //  48 KB
    __shared__ alignas(16) u16 Bs[3][256 * 64];   //  96 KB
    int tid = threadIdx.x, lane = tid & 63, wave = tid >> 6;   // 8 waves
    // T1 XCD-aware bijective remap of the 16x16 tile grid
    int f = blockIdx.y * 16 + blockIdx.x;
    int xcd = f & 7, bi = f >> 3;
    int by = xcd * 2 + (bi & 1);
    int bx = bi >> 1;
    int row0 = by * 128, col0 = bx * 256;
    int wr = (wave >> 1) * 32;        // 4 M row-groups
    int wc = (wave & 1) * 128;        // 2 N head-columns
    int l15 = lane & 15, lg = lane >> 4;

    f32x4 acc[2][8] = {};

    auto stage = [&](int bf, int k0) {
#pragma unroll
        for (int i = 0; i < 2; i++) {
            int slot = i * 8 + wave;                 // 0..15 (wave-uniform)
            int r = slot * 8 + (lane >> 3);          // A row 0..127
            int c = (lane & 7) ^ (r & 7);            // inverse-swizzled source chunk
            __builtin_amdgcn_global_load_lds(AS1(A + (size_t)(row0 + r) * K + k0 + c * 8),
                                             AS3(&As[bf][slot * 512]), 16, 0, 0);
        }
#pragma unroll
        for (int i = 0; i < 4; i++) {
            int slot = i * 8 + wave;                 // 0..31
            int r = slot * 8 + (lane >> 3);          // B row 0..255
            int c = (lane & 7) ^ (r & 7);
            __builtin_amdgcn_global_load_lds(AS1(B + (size_t)(col0 + r) * K + k0 + c * 8),
                                             AS3(&Bs[bf][slot * 512]), 16, 0, 0);
        }
    };

    const int nk = K >> 6;            // 32
    stage(0, 0);
    stage(1, 64);

    for (int t = 0; t < nk; ++t) {
        int buf = t % 3;
        __builtin_amdgcn_sched_barrier(0);
        if (t + 1 < nk) PIPE_WAIT6(); else PIPE_WAIT0();
        if (t + 2 < nk) stage((t + 2) % 3, (t + 2) * 64);

        __builtin_amdgcn_s_setprio(1);
#pragma unroll
        for (int kk = 0; kk < 2; kk++) {
            bf16x8 af[2], bg[8];
#pragma unroll
            for (int m = 0; m < 2; m++) {
                int r = wr + m * 16 + l15;
                af[m] = *reinterpret_cast<const bf16x8*>(&As[buf][r * 64 + (((kk * 4 + lg) ^ (r & 7)) * 8)]);
            }
#pragma unroll
            for (int n = 0; n < 8; n++) {
                int r = wc + n * 16 + l15;
                bg[n] = *reinterpret_cast<const bf16x8*>(&Bs[buf][r * 64 + (((kk * 4 + lg) ^ (r & 7)) * 8)]);
            }
#pragma unroll
            for (int m = 0; m < 2; m++)
#pragma unroll
                for (int n = 0; n < 8; n++)
                    acc[m][n] = __builtin_amdgcn_mfma_f32_16x16x32_bf16(af[m], bg[n], acc[m][n], 0, 0, 0);
        }
        __builtin_amdgcn_s_setprio(0);
    }

    // epilogue (round-8 verified; head column c32 per-wave uniform)
    int c32 = bx * 2 + (wave & 1);   // 0..15 Q, 16..23 K, 24..31 V
    if (c32 < 24) {
        bool isQ = c32 < 16;
        float w2[8];
        if (isQ) {
#pragma unroll
            for (int j = 0; j < 8; j++) {
                float w = sqkw[c32 * 128 + j * 16 + l15] * 50.f;
                w2[j] = w * w * QSCALE_LOG2E;
            }
        }
        u16* outb = isQ ? (qb + (size_t)c32 * S_LEN * 128)
                        : (kb + (size_t)(c32 - 16) * S_LEN * 128);
#pragma unroll
        for (int m = 0; m < 2; m++)
#pragma unroll
            for (int r = 0; r < 4; r++) {
                int s = row0 + wr + m * 16 + lg * 4 + r;
                const float* crow = cosb + (size_t)s * 128;
                const float* srow = sinb + (size_t)s * 128;
                float y[8];
                float ss = 0.f;
#pragma unroll
                for (int j = 0; j < 4; j++) {
                    float c  = crow[j * 16 + l15];
                    float sn = srow[j * 16 + l15];
                    float x0 = acc[m][j][r], x1 = acc[m][j + 4][r];
                    float a = x0 * c - x1 * sn;
                    float b = x1 * c + x0 * sn;
                    y[j] = a; y[j + 4] = b;
                    ss += a * a + b * b;
                }
                ss += __shfl_xor(ss, 1);
                ss += __shfl_xor(ss, 2);
                ss += __shfl_xor(ss, 4);
                ss += __shfl_xor(ss, 8);
                float inv = 1.f / (sqrtf(ss) + 1e-8f);
                u16* orow = outb + (size_t)s * 128;
                if (isQ) {
#pragma unroll
                    for (int j = 0; j < 8; j++)
                        orow[j * 16 + l15] = f2b(y[j] * inv * w2[j]);
                } else {
#pragma unroll
                    for (int j = 0; j < 8; j++)
                        orow[j * 16 + l15] = f2b(y[j] * inv);
                }
            }
    } else {
        int g = c32 - 24;
#pragma unroll
        for (int n = 0; n < 8; n++) {
            int d = n * 16 + l15;
            u16* vrow = vt + (size_t)(g * 128 + d) * S_LEN;
#pragma unroll
            for (int m = 0; m < 2; m++) {
                u16x4 pk;
#pragma unroll
                for (int r = 0; r < 4; r++) pk[r] = f2b(acc[m][n][r]);
                *reinterpret_cast<u16x4*>(&vrow[row0 + wr + m * 16 + lg * 4]) = pk;
            }
        }
    }
}

// ---------------------------------------------------------------- O-proj GEMM (r11 3-buf counted pipeline, 128x64, 4 waves)
__global__ __launch_bounds__(256) void gemm_o(const u16* __restrict__ A,
                                              const u16* __restrict__ B,
                                              float* __restrict__ C,
                                              int M, int N, int K) {
    __shared__ alignas(16) u16 As[3][128 * 64];   // 48 KB
    __shared__ alignas(16) u16 Bs[3][64 * 64];    // 24 KB
    int tid = threadIdx.x, lane = tid & 63, wave = tid >> 6;   // 4 waves
    int row0 = blockIdx.y * 128, col0 = blockIdx.x * 64;
    int wr = wave * 32;               // 4M x 1N wave grid
    int l15 = lane & 15, lg = lane >> 4;

    f32x4 acc[2][4] = {};

    auto stage = [&](int bf, int k0) {
#pragma unroll
        for (int i = 0; i < 4; i++) {
            int slot = i * 4 + wave;                 // 0..15
            int r = slot * 8 + (lane >> 3);          // A row 0..127
            int c = (lane & 7) ^ (r & 7);
            __builtin_amdgcn_global_load_lds(AS1(A + (size_t)(row0 + r) * K + k0 + c * 8),
                                             AS3(&As[bf][slot * 512]), 16, 0, 0);
        }
#pragma unroll
        for (int i = 0; i < 2; i++) {
            int slot = i * 4 + wave;                 // 0..7
            int r = slot * 8 + (lane >> 3);          // B row 0..63
            int c = (lane & 7) ^ (r & 7);
            __builtin_amdgcn_global_load_lds(AS1(B + (size_t)(col0 + r) * K + k0 + c * 8),
                                             AS3(&Bs[bf][slot * 512]), 16, 0, 0);
        }
    };

    const int nk = K >> 6;
    stage(0, 0);
    stage(1, 64);

    for (int t = 0; t < nk; ++t) {
        int buf = t % 3;
        __builtin_amdgcn_sched_barrier(0);
        if (t + 1 < nk) PIPE_WAIT6(); else PIPE_WAIT0();
        if (t + 2 < nk) stage((t + 2) % 3, (t + 2) * 64);

        __builtin_amdgcn_s_setprio(1);
#pragma unroll
        for (int kk = 0; kk < 2; kk++) {
            bf16x8 af[2], bg[4];
#pragma unroll
            for (int m = 0; m < 2; m++) {
                int r = wr + m * 16 + l15;
                af[m] = *reinterpret_cast<const bf16x8*>(&As[buf][r * 64 + (((kk * 4 + lg) ^ (r & 7)) * 8)]);
            }
#pragma unroll
            for (int n = 0; n < 4; n++) {
                int r = n * 16 + l15;
                bg[n] = *reinterpret_cast<const bf16x8*>(&Bs[buf][r * 64 + (((kk * 4 + lg) ^ (r & 7)) * 8)]);
            }
#pragma unroll
            for (int m = 0; m < 2; m++)
#pragma unroll
                for (int n = 0; n < 4; n++)
                    acc[m][n] = __builtin_amdgcn_mfma_f32_16x16x32_bf16(af[m], bg[n], acc[m][n], 0, 0, 0);
        }
        __builtin_amdgcn_s_setprio(0);
    }

#pragma unroll
    for (int m = 0; m < 2; m++)
#pragma unroll
        for (int n = 0; n < 4; n++)
#pragma unroll
            for (int r = 0; r < 4; r++) {
                int row = row0 + wr + m * 16 + lg * 4 + r;
                int col = col0 + n * 16 + l15;
                C[(size_t)row * N + col] = acc[m][n][r];
            }
}

// ---------------------------------------------------------------- MFMA flash attention (r12: LDS-staged + XCD remap)
__global__ __launch_bounds__(256) void attn_mfma(const u16* __restrict__ Qb,  // [16][S][128]
                                                 const u16* __restrict__ Kb,  // [8][S][128]
                                                 const u16* __restrict__ Vt,  // [1024][S]
                                                 u16* __restrict__ Ao) {      // [S][2048]
    __shared__ alignas(16) char smem[50432];
    u16* Ks = (u16*)smem;                      // [64][256B] 16KB (loop)
    u16* Vs = (u16*)(smem + 16384);            // [128][128B] 16KB (loop)
    float* scrO = (float*)smem;                // [2][128][32] f32 32KB (epilogue)
    float* scrL = (float*)(smem + 32768);      // [2][32] f32 (epilogue)
    u16*   scrT = (u16*)(smem + 33024);        // [64][136] u16 (epilogue)

    int tid = threadIdx.x, lane = tid & 63, wv = tid >> 6;
    int b = blockIdx.x;
    int xcd = b & 7, j = b >> 3;
    int g = xcd;
    int h = xcd * 2 + (j & 1);
    int z = j >> 1;                            // 0..31
    int qi = (z < 16) ? (31 - z) : (z - 16);   // pair big+small per CU
    int qb0 = qi * 64;
    int l31 = lane & 31, hi = lane >> 5;
    int qoff = (wv >> 1) * 32, koff = (wv & 1) * 32;
    int qabs = qb0 + qoff + l31;

    bf16x8 qf[8];
    {
        const u16* qrow = Qb + ((size_t)h * S_LEN + qabs) * 128;
#pragma unroll
        for (int kd = 0; kd < 8; kd++)
            qf[kd] = *reinterpret_cast<const bf16x8*>(qrow + kd * 16 + hi * 8);
    }

    const u16* kbase = Kb + (size_t)g * S_LEN * 128;
    const u16* vbase = Vt + (size_t)g * 128 * S_LEN;

    int rk = wv * 16 + (lane >> 4);
    int ck = lane & 15;
    int rv = wv * 32 + (lane >> 3);
    int cv = lane & 7;

    u16x8 kreg[4], vreg[4];
    f32x16 oacc[4] = {};
    float lpart = 0.f;

    int nt = qi + 1;

#pragma unroll
    for (int i = 0; i < 4; i++) {
        kreg[i] = *reinterpret_cast<const u16x8*>(kbase + (size_t)(rk + 4 * i) * 128 + ck * 8);
        vreg[i] = *reinterpret_cast<const u16x8*>(vbase + (size_t)(rv + 8 * i) * S_LEN + cv * 8);
    }

    for (int t = 0; t < nt; ++t) {
        int k0 = t * 64;
        __syncthreads();
#pragma unroll
        for (int i = 0; i < 4; i++) {
            int r = rk + 4 * i;
            *reinterpret_cast<u16x8*>((char*)Ks + r * 256 + ((ck * 16) ^ SWZK(r))) = kreg[i];
            int r2 = rv + 8 * i;
            *reinterpret_cast<u16x8*>((char*)Vs + r2 * 128 + ((cv * 16) ^ SWZV(r2))) = vreg[i];
        }
        __syncthreads();

        if (t + 1 < nt) {
            int kn = k0 + 64;
#pragma unroll
            for (int i = 0; i < 4; i++) {
                kreg[i] = *reinterpret_cast<const u16x8*>(kbase + (size_t)(kn + rk + 4 * i) * 128 + ck * 8);
                vreg[i] = *reinterpret_cast<const u16x8*>(vbase + (size_t)(rv + 8 * i) * S_LEN + kn + cv * 8);
            }
        }

        f32x16 s0 = {}, s1 = {};
        int krow = koff + l31;
        char* krp = (char*)Ks + krow * 256;
        int ksw = SWZK(krow);
        __builtin_amdgcn_s_setprio(1);
#pragma unroll
        for (int kd = 0; kd < 8; kd += 2) {
            bf16x8 kf0 = *reinterpret_cast<const bf16x8*>(krp + ((kd * 32 + hi * 16) ^ ksw));
            bf16x8 kf1 = *reinterpret_cast<const bf16x8*>(krp + (((kd + 1) * 32 + hi * 16) ^ ksw));
            s0 = __builtin_amdgcn_mfma_f32_32x32x16_bf16(kf0, qf[kd], s0, 0, 0, 0);
            s1 = __builtin_amdgcn_mfma_f32_32x32x16_bf16(kf1, qf[kd + 1], s1, 0, 0, 0);
        }
        __builtin_amdgcn_s_setprio(0);

        float p[16];
        bool maskt = (t == nt - 1);
#pragma unroll
        for (int r = 0; r < 16; r++) {
            float s = s0[r] + s1[r];
            if (maskt) {
                int key = k0 + koff + (r & 3) + 8 * (r >> 2) + 4 * hi;
                if (key > qabs) s = -1e30f;
            }
            float pv = EXP2(s - M2INIT);
            p[r] = pv;
            lpart += pv;
        }

        bf16x8 pf[2];
#pragma unroll
        for (int ks = 0; ks < 2; ks++) {
            int bb = ks * 8;
            unsigned int A0 = (unsigned int)f2b(p[bb + 0]) | ((unsigned int)f2b(p[bb + 1]) << 16);
            unsigned int A1 = (unsigned int)f2b(p[bb + 2]) | ((unsigned int)f2b(p[bb + 3]) << 16);
            unsigned int A2 = (unsigned int)f2b(p[bb + 4]) | ((unsigned int)f2b(p[bb + 5]) << 16);
            unsigned int A3 = (unsigned int)f2b(p[bb + 6]) | ((unsigned int)f2b(p[bb + 7]) << 16);
            unsigned int S0 = __shfl_xor(A0, 32);
            unsigned int S1 = __shfl_xor(A1, 32);
            unsigned int S2 = __shfl_xor(A2, 32);
            unsigned int S3 = __shfl_xor(A3, 32);
            u32x4 w;
            w[0] = hi ? S2 : A0;
            w[1] = hi ? S3 : A1;
            w[2] = hi ? A2 : S0;
            w[3] = hi ? A3 : S1;
            pf[ks] = *reinterpret_cast<bf16x8*>(&w);
        }

        __builtin_amdgcn_s_setprio(1);
#pragma unroll
        for (int db = 0; db < 4; db++) {
            int vr = db * 32 + l31;
            char* vrp = (char*)Vs + vr * 128;
            int vsw = SWZV(vr);
#pragma unroll
            for (int ks = 0; ks < 2; ks++) {
                bf16x8 vf = *reinterpret_cast<const bf16x8*>(vrp + ((koff * 2 + ks * 32 + hi * 16) ^ vsw));
                oacc[db] = __builtin_amdgcn_mfma_f32_32x32x16_bf16(vf, pf[ks], oacc[db], 0, 0, 0);
            }
        }
        __builtin_amdgcn_s_setprio(0);
    }

    float lw = lpart + __shfl_xor(lpart, 32);
    int rg = wv >> 1;
    __syncthreads();
    if (wv & 1) {
#pragma unroll
        for (int db = 0; db < 4; db++)
#pragma unroll
            for (int r = 0; r < 16; r++) {
                int d = db * 32 + (r & 3) + 8 * (r >> 2) + 4 * hi;
                scrO[(rg * 128 + d) * 32 + l31] = oacc[db][r];
            }
        if (lane < 32) scrL[rg * 32 + l31] = lw;
    }
    __syncthreads();
    if (!(wv & 1)) {
        float inv = 1.f / (lw + scrL[rg * 32 + l31]);
#pragma unroll
        for (int db = 0; db < 4; db++)
#pragma unroll
            for (int r = 0; r < 16; r++) {
                int d = db * 32 + (r & 3) + 8 * (r >> 2) + 4 * hi;
                float o = (oacc[db][r] + scrO[(rg * 128 + d) * 32 + l31]) * inv;
                scrT[(rg * 32 + l31) * 136 + d] = f2b(o);
            }
    }
    __syncthreads();
    for (int i = tid; i < 64 * 16; i += 256) {
        int q = i >> 4, c = i & 15;
        u16x8 v = *reinterpret_cast<const u16x8*>(&scrT[q * 136 + c * 8]);
        *reinterpret_cast<u16x8*>(&Ao[(size_t)(qb0 + q) * 2048 + h * 128 + c * 8]) = v;
    }
}

// ---------------------------------------------------------------- launch
extern "C" void kernel_launch(void* const* d_in, const int* in_sizes, int n_in,
                              void* d_out, int out_size, void* d_ws, size_t ws_size,
                              hipStream_t stream) {
    const float* hs   = (const float*)d_in[0];
    const float* cosb = (const float*)d_in[1];
    const float* sinb = (const float*)d_in[2];
    // d_in[3] attention_mask: pure causal, implemented analytically
    const float* Wq   = (const float*)d_in[4];
    const float* Wk   = (const float*)d_in[5];
    const float* Wv   = (const float*)d_in[6];
    const float* Wo   = (const float*)d_in[7];
    const float* sqkw = (const float*)d_in[8];

    char* ws = (char*)d_ws;
    u16*   hsb  = (u16*)(ws);                       //  8.4 MB
    u16*   wcat = (u16*)(ws + 8388608);             // 16.8 MB (Wq;Wk;Wv)
    u16*   wob  = (u16*)(ws + 25165824);            //  8.4 MB
    u16*   qb   = (u16*)(ws + 33554432);            //  8.4 MB  [16][S][128]
    u16*   kb   = (u16*)(ws + 41943040);            //  4.2 MB  [8][S][128]
    u16*   vt   = (u16*)(ws + 46137344);            //  4.2 MB  [1024][S] (V^T)
    u16*   ao   = (u16*)(ws + 50331648);            //  8.4 MB  [S][2048]

    cast_all<<<16384, 256, 0, stream>>>(hs, Wq, Wk, Wv, Wo, hsb, wcat, wob);

    // fused QKV projection + RoPE + L2 norm + sqk scale + V transpose
    gemm_qkv<<<dim3(16, 16), 512, 0, stream>>>(hsb, wcat, cosb, sinb, sqkw, qb, kb, vt);

    attn_mfma<<<512, 256, 0, stream>>>(qb, kb, vt, ao);

    // output projection -> f32 d_out (128x64 tiles, 4 waves, 512 blocks = 2/CU)
    gemm_o<<<dim3(32, 16), 256, 0, stream>>>(ao, wob, (float*)d_out, 2048, 2048, 2048);
}